// Round 2
// baseline (324.610 us; speedup 1.0000x reference)
//
#include <hip/hip_runtime.h>

// out[n,c,j,i] = x[n, c, clamp(j + sy - 4, 0, 127), clamp(i + sx - 4, 0, 127)]
// where (sx, sy) = shift[n]. Pure memory-bound shifted copy.
// This version: all-aligned float4 loads (dual-load + compile-time blend on
// r = dx&3, which is wave-uniform -> scalar branch), NT stores.

constexpr int Himg = 128;   // height = width = 128
constexpr int Cimg = 12;    // channels
constexpr int PADc = 4;     // PADDING

using f4 = __attribute__((ext_vector_type(4))) float;

template <int R>
__device__ __forceinline__ f4 blend(f4 a, f4 b) {
    // out[e] = concat(a,b)[R+e], all indices compile-time
    const float arr[8] = {a[0], a[1], a[2], a[3], b[0], b[1], b[2], b[3]};
    f4 v;
    v[0] = arr[R + 0];
    v[1] = arr[R + 1];
    v[2] = arr[R + 2];
    v[3] = arr[R + 3];
    return v;
}

__global__ __launch_bounds__(256) void random_shift_kernel(
    const float* __restrict__ x,
    const int* __restrict__ shift,
    float* __restrict__ out)
{
    // grid: (Cimg*Himg*Himg/4/256, N) = (192, 256)
    const int n     = blockIdx.y;
    const int flat4 = blockIdx.x * 256 + threadIdx.x;   // [0, 12*128*32)
    const int col4  = flat4 & 31;                        // which float4 in row
    const int rowi  = flat4 >> 5;                        // [0, 12*128)
    const int j     = rowi & (Himg - 1);                 // row within image
    const int cc    = rowi >> 7;                         // channel

    // per-image shift: uniform across the block; force SGPR so branches on it
    // are scalar (s_cbranch), not divergent
    const int sx = __builtin_amdgcn_readfirstlane(shift[2 * n]);
    const int sy = __builtin_amdgcn_readfirstlane(shift[2 * n + 1]);
    const int dx = sx - PADc;   // in [-4, 4]
    const int dy = sy - PADc;

    int sj = j + dy;
    sj = sj < 0 ? 0 : (sj > Himg - 1 ? Himg - 1 : sj);

    const long long img_base = (long long)(n * Cimg + cc) * (Himg * Himg);
    const float* __restrict__ src_row = x + img_base + (long long)sj * Himg;
    float* dst = out + img_base + (long long)j * Himg + col4 * 4;

    const int i0 = col4 * 4 + dx;   // leftmost source column for this float4
    f4 v;
    if (i0 >= 0 && i0 + 3 <= Himg - 1) {
        const int r = dx & 3;       // wave-uniform (SGPR)
        const int q = i0 - r;       // 16B-aligned base; q>=0, q+7<=127 when r!=0
        if (r == 0) {
            v = *reinterpret_cast<const f4*>(src_row + q);
        } else {
            const f4 A = *reinterpret_cast<const f4*>(src_row + q);
            const f4 B = *reinterpret_cast<const f4*>(src_row + q + 4);
            switch (r) {
                case 1:  v = blend<1>(A, B); break;
                case 2:  v = blend<2>(A, B); break;
                default: v = blend<3>(A, B); break;
            }
        }
    } else {
        // row edge: clamp each of the 4 source columns (<= 2 lanes per wave-half)
        int a = i0, b = i0 + 1, c2 = i0 + 2, d = i0 + 3;
        a  = a  < 0 ? 0 : (a  > Himg - 1 ? Himg - 1 : a);
        b  = b  < 0 ? 0 : (b  > Himg - 1 ? Himg - 1 : b);
        c2 = c2 < 0 ? 0 : (c2 > Himg - 1 ? Himg - 1 : c2);
        d  = d  < 0 ? 0 : (d  > Himg - 1 ? Himg - 1 : d);
        v[0] = src_row[a]; v[1] = src_row[b]; v[2] = src_row[c2]; v[3] = src_row[d];
    }
    __builtin_nontemporal_store(v, reinterpret_cast<f4*>(dst));
}

extern "C" void kernel_launch(void* const* d_in, const int* in_sizes, int n_in,
                              void* d_out, int out_size, void* d_ws, size_t ws_size,
                              hipStream_t stream) {
    const float* x     = (const float*)d_in[0];
    const int*   shift = (const int*)d_in[1];
    float*       out   = (float*)d_out;

    const int N = 256;
    // per image: Cimg*Himg*Himg/4 float4s = 49152 -> 192 blocks of 256 threads
    dim3 grid(Cimg * Himg * (Himg / 4) / 256, N);
    random_shift_kernel<<<grid, 256, 0, stream>>>(x, shift, out);
}